// Round 2
// baseline (131.792 us; speedup 1.0000x reference)
//
#include <hip/hip_runtime.h>
#include <math.h>

// RandomLowRes2D: per-image Gaussian blur (R=15, symmetric pad) + linear
// down/up resample along a per-image runtime axis.
//
// Fusion: low[j] = (1-fr)*s[la] + fr*s[la+1] collapses blur+downsample into a
// single fused filter on img: cw[k] = fmaf(fr, dwe[k], we[k+1]),
// with dwe[k] = we[k] - we[k+1] precomputed.
//
// Round 6 (ax0 restructured to "mode B" — cooperative low rows in LDS):
//  - ax0: instead of per-4-row-group rolling register lows (which recomputed
//    every low row 2-4x across groups/blocks and issued (2kr+2) float4 loads
//    per group per low), the whole 256-thread block now computes each needed
//    low row ONCE (float2/lane = 512 cols, position math block-uniform),
//    stores <=9 rows in LDS, syncs, then upsamples 8 output rows from LDS.
//    Heavy-res blocks: ~4x fewer VMEM instructions and ~4x less L1/L2 reread.
//  - All ax0 LDS traffic is stride-1 conflict-free; upsample divides are
//    8 per block-row (scalar-uniform) instead of 5 per lane.
//  - ax1 path unchanged from round 5.
//  - LDS overlaid: ax0 lowB[9][512] reuses ax1's s_img/s_low space (18.7 KB
//    -> still 8 blocks/CU, 32 waves).

#define RR 15
#define TAPS 31
#define SIG_PER_FWHM 0.42466090014400953f  // 1/sqrt(8 ln 2)

__global__ __launch_bounds__(256) void lowres2d_kernel(
    const float* __restrict__ x,
    const float* __restrict__ resolution,
    const int*   __restrict__ axis,
    const float* __restrict__ gap,
    float* __restrict__ out)
{
    const int tid = threadIdx.x;
    const int n   = blockIdx.y;          // image index
    const int bx  = blockIdx.x;          // 0..127

    const float res = resolution[n];
    const int   ax  = axis[n];
    const float gp  = gap[n];

    // ax0 images use 64 blocks of 8 rows; rest exit (block-uniform)
    if (ax == 0 && bx >= 64) return;

    const float sig = fmaxf(res * gp * SIG_PER_FWHM, 1e-6f);
    int n_low = (int)floorf(512.0f / res);
    if (n_low < 1) n_low = 1;
    if (n_low > 512) n_low = 512;
    const float nlm1f = (float)(n_low - 1);

    // adaptive radius: normalized weights < 1e-6 outside +-kr (sum >= 1)
    int kr = (int)(sig * 5.2565f) + 1;
    if (kr > RR) kr = RR;
    const int k0 = RR - kr, k1 = RR + 1 + kr;   // fused window k in [k0, k1]
    const int la_lo = kr, la_hi = 510 - kr;     // interior: no reflect needed

    // wd[k] = { we[k+1], dwe[k] }, k = 0..31; we[0]=we[32]=0 implicit
    __shared__ float2 wd[32];
    // overlaid scratch: ax1 uses s_img[4][520] + s_low[4][516] (4144 floats),
    // ax0 uses s_lowB[9][512] (4608 floats)
    __shared__ float smem[4608];
    float (*s_img)[520]  = (float (*)[520])smem;
    float (*s_low)[516]  = (float (*)[516])(smem + 4 * 520);
    float (*s_lowB)[512] = (float (*)[512])smem;

    if (tid < 32) {
        const int k = tid;
        float r = 0.0f;
        if (k < TAPS) {
            float d = (float)(k - RR) / sig;
            r = expf(-0.5f * d * d);
        }
        float tot = r;
        tot += __shfl_xor(tot, 1, 32);
        tot += __shfl_xor(tot, 2, 32);
        tot += __shfl_xor(tot, 4, 32);
        tot += __shfl_xor(tot, 8, 32);
        tot += __shfl_xor(tot, 16, 32);
        float rm1 = __shfl_up(r, 1, 32);
        if (k == 0) rm1 = 0.0f;
        const float inv = 1.0f / tot;            // tot >= 1 (center tap)
        wd[k] = make_float2(r * inv, (rm1 - r) * inv);
    }
    __syncthreads();

    const size_t base = (size_t)n * (512 * 512);
    const float* img = x + base;
    float* o = out + base;

    if (ax == 0) {
        // ---- ax0 mode B: block-cooperative low rows in LDS ----
        const int i0 = bx * 8;
        const int c  = tid;                      // column pair: cols 2c, 2c+1
        const float2* img2 = (const float2*)img;
        float2* out2 = (float2*)o;

        // needed low rows for output rows [i0, i0+8)
        float pA = fminf((float)i0 / res, nlm1f);
        int jlo = (int)floorf(pA);
        float pB = fminf((float)(i0 + 7) / res, nlm1f);
        int jhi = (int)floorf(pB) + 1;
        if (jhi > n_low - 1) jhi = n_low - 1;
        if (jhi < jlo) jhi = jlo;
        // jhi - jlo <= floor(7/res) + 1 <= 8  ->  <= 9 rows

        for (int j = jlo; j <= jhi; ++j) {       // block-uniform loop
            float pos = fminf((float)j * res, 511.0f);
            float lof = floorf(pos);
            float fr  = pos - lof;
            int   la  = (int)lof;
            float2 acc = make_float2(0.0f, 0.0f);
            if (la >= la_lo && la <= la_hi) {    // block-uniform branch
                #pragma unroll 4
                for (int k = k0; k <= k1; ++k) {
                    int t = la - RR + k;
                    float2 w = wd[k];
                    float cw = fmaf(fr, w.y, w.x);
                    float2 v = img2[(size_t)(t * 256 + c)];
                    acc.x = fmaf(cw, v.x, acc.x);
                    acc.y = fmaf(cw, v.y, acc.y);
                }
            } else {
                for (int k = k0; k <= k1; ++k) {
                    int t = la - RR + k;
                    t = (t < 0)   ? (-1 - t)   : t;  // symmetric reflect
                    t = (t > 511) ? (1023 - t) : t;
                    float2 w = wd[k];
                    float cw = fmaf(fr, w.y, w.x);
                    float2 v = img2[(size_t)(t * 256 + c)];
                    acc.x = fmaf(cw, v.x, acc.x);
                    acc.y = fmaf(cw, v.y, acc.y);
                }
            }
            ((float2*)&s_lowB[j - jlo][0])[c] = acc;
        }
        __syncthreads();

        #pragma unroll
        for (int ii = 0; ii < 8; ++ii) {
            int i = i0 + ii;
            float pos2 = fminf((float)i / res, nlm1f);  // exact IEEE div
            float l2f  = floorf(pos2);
            float fr2  = pos2 - l2f;
            int lo2 = (int)l2f;                  // <= n_low-1 (pos2 clamped)
            int hi2 = (lo2 + 1 <= jhi) ? (lo2 + 1) : jhi;  // == min(lo2+1, n_low-1)
            float2 A = ((float2*)&s_lowB[lo2 - jlo][0])[c];
            float2 B = ((float2*)&s_lowB[hi2 - jlo][0])[c];
            float omf2 = 1.0f - fr2;
            out2[(size_t)(i * 256 + c)] =
                make_float2(A.x * omf2 + B.x * fr2,
                            A.y * omf2 + B.y * fr2);
        }
    } else {
        // ---------------- ax1: LDS-tiled 4 rows, coalesced ----------------
        const int h0 = bx * 4;

        // load 4x512 tile, float4 coalesced (512 float4 over 256 threads)
        const float4* img4 = (const float4*)(img + (size_t)h0 * 512);
        #pragma unroll
        for (int p = 0; p < 2; ++p) {
            int m = p * 256 + tid;
            int r = m >> 7, c4 = m & 127;
            ((float4*)&s_img[r][0])[c4] = img4[r * 128 + c4];
        }
        __syncthreads();

        // compute lows: one wave per row (r uniform per wave), j strided 64
        {
            const int r = __builtin_amdgcn_readfirstlane(tid >> 6);
            for (int j = (tid & 63); j < n_low; j += 64) {
                float pos = fminf((float)j * res, 511.0f);
                float lof = floorf(pos);
                float fr  = pos - lof;
                int   la  = (int)lof;
                float acc = 0.0f;
                if (la >= la_lo && la <= la_hi) {
                    #pragma unroll 4
                    for (int k = k0; k <= k1; ++k) {
                        int t = la - RR + k;
                        float2 w = wd[k];
                        float cw = fmaf(fr, w.y, w.x);
                        acc = fmaf(cw, s_img[r][t], acc);
                    }
                } else {
                    for (int k = k0; k <= k1; ++k) {
                        int t = la - RR + k;
                        t = (t < 0)   ? (-1 - t)   : t;
                        t = (t > 511) ? (1023 - t) : t;
                        float2 w = wd[k];
                        float cw = fmaf(fr, w.y, w.x);
                        acc = fmaf(cw, s_img[r][t], acc);
                    }
                }
                s_low[r][j] = acc;
            }
        }
        __syncthreads();

        // upsample + coalesced float4 stores
        float4* out4 = (float4*)(o + (size_t)h0 * 512);
        #pragma unroll
        for (int p = 0; p < 2; ++p) {
            int m = p * 256 + tid;
            int r = m >> 7, c4 = m & 127;
            float vals[4];
            #pragma unroll
            for (int q = 0; q < 4; ++q) {
                int i = c4 * 4 + q;
                float pos2 = fminf((float)i / res, nlm1f);
                float l2f  = floorf(pos2);
                float fr2  = pos2 - l2f;
                int lo2 = (int)l2f;
                if (lo2 > n_low - 1) lo2 = n_low - 1;
                int hi2 = (lo2 + 1 < n_low) ? (lo2 + 1) : (n_low - 1);
                vals[q] = s_low[r][lo2] * (1.0f - fr2) + s_low[r][hi2] * fr2;
            }
            float4 ov;
            ov.x = vals[0]; ov.y = vals[1]; ov.z = vals[2]; ov.w = vals[3];
            out4[r * 128 + c4] = ov;
        }
    }
}

extern "C" void kernel_launch(void* const* d_in, const int* in_sizes, int n_in,
                              void* d_out, int out_size, void* d_ws, size_t ws_size,
                              hipStream_t stream) {
    const float* x          = (const float*)d_in[0];
    const float* resolution = (const float*)d_in[1];
    const int*   axis       = (const int*)d_in[2];
    const float* gap        = (const float*)d_in[3];
    float* out = (float*)d_out;

    const int n_img = in_sizes[1];   // B*C = 64

    dim3 grid(128, n_img);
    lowres2d_kernel<<<grid, 256, 0, stream>>>(x, resolution, axis, gap, out);
}